// Round 4
// baseline (5883.838 us; speedup 1.0000x reference)
//
#include <hip/hip_runtime.h>
#include <cmath>

#define BB 64
#define TT 2048
#define FF 64
#define HH 160
#define G3 480
#define TC 256            // time-chunk length
#define NC (TT / TC)      // 8 chunks

typedef unsigned int u32;
typedef _Float16 half2v __attribute__((ext_vector_type(2)));

__device__ __forceinline__ unsigned short f2h(float x) {
    _Float16 h = (_Float16)x;
    return __builtin_bit_cast(unsigned short, h);
}
__device__ __forceinline__ u32 packh2(float a, float b) {
    return (u32)f2h(a) | ((u32)f2h(b) << 16);
}
__device__ __forceinline__ float fdot2(u32 w, u32 v, float acc) {
    return __builtin_amdgcn_fdot2(__builtin_bit_cast(half2v, w),
                                  __builtin_bit_cast(half2v, v), acc, false);
}
__device__ __forceinline__ u32 rdlane(u32 v, int l) {
    return (u32)__builtin_amdgcn_readlane((int)v, l);
}
__device__ __forceinline__ float fsigmoid(float x) { return 1.f / (1.f + __expf(-x)); }
__device__ __forceinline__ float ftanhf(float x) {
    float xc = fminf(fmaxf(x, -15.f), 15.f);
    float e = __expf(2.f * xc);
    return 1.f - 2.f / (e + 1.f);
}
__device__ __forceinline__ float gelu_exact(float x) {
    return 0.5f * x * (1.f + erff(x * 0.70710678118654752f));
}

// ---------------------------------------------------------------------------
// K1: dilated conv (k=3, dil=2, pad=2) + BN + exact GELU -> z f16 pairs [B,T,32]u32
// (unchanged — passed R1/R3)
// ---------------------------------------------------------------------------
__global__ __launch_bounds__(256) void conv_bn_gelu_kernel(
    const float* __restrict__ x, const float* __restrict__ mix_w,
    const float* __restrict__ bn_g, const float* __restrict__ bn_b,
    const float* __restrict__ bn_m, const float* __restrict__ bn_v,
    u32* __restrict__ z_out)
{
    __shared__ float ws_w[3][64][64];
    __shared__ float ws_x[132][64];
    const int b  = blockIdx.y;
    const int t0 = blockIdx.x * 128;
    const int tid = threadIdx.x;
    const int f  = tid & 63;
    const int rg = tid >> 6;

    for (int idx = tid; idx < 64 * 64 * 3; idx += 256) {
        int fo = idx / 192;
        int rem = idx - fo * 192;
        int fi = rem / 3;
        int k  = rem - fi * 3;
        ws_w[k][fi][fo] = mix_w[idx];
    }
    for (int row = rg; row < 132; row += 4) {
        int t = t0 - 2 + row;
        ws_x[row][f] = (t >= 0 && t < TT) ? x[((size_t)b * TT + t) * FF + f] : 0.f;
    }
    __syncthreads();

    const float scale = bn_g[f] * rsqrtf(bn_v[f] + 1e-5f);
    const float shift = bn_b[f] - bn_m[f] * scale;

    for (int ti = rg; ti < 128; ti += 4) {
        float acc = 0.f;
        #pragma unroll
        for (int k = 0; k < 3; ++k) {
            const float* xr = &ws_x[ti + 2 * k][0];
            #pragma unroll
            for (int fi = 0; fi < 64; ++fi)
                acc = fmaf(xr[fi], ws_w[k][fi][f], acc);
        }
        float y = fmaf(acc, scale, shift);
        float z = gelu_exact(y);
        float zp = __shfl_xor(z, 1);
        if ((f & 1) == 0)
            z_out[((size_t)b * TT + (t0 + ti)) * 32 + (f >> 1)] = packh2(z, zp);
    }
}

// ---------------------------------------------------------------------------
// K2: readlane GEMM, 1 gate-row/thread (no spill: w[K2] + zr[K2/4] uint4).
// Every wave holds the 64-row activation tile (lane = row); rows broadcast
// via v_readlane. grid (TC/64, B), block 512, 480 workers.
// ---------------------------------------------------------------------------
template<int K2>
__global__ __launch_bounds__(512, 2) void xg_gemm_kernel(
    const u32* __restrict__ in, int in_stride_rows, int row0,
    const float* __restrict__ W, const float* __restrict__ bias,
    float* __restrict__ out)
{
    const int tid  = threadIdx.x;
    const int lane = tid & 63;
    const int b    = blockIdx.y;
    const int mt   = blockIdx.x;
    const size_t in_row   = (size_t)b * in_stride_rows + row0 + mt * 64 + lane;
    const size_t out_base = ((size_t)b * TC + mt * 64) * G3;

    uint4 zr[K2 / 4];
    const uint4* gz = (const uint4*)(in + in_row * K2);
    #pragma unroll
    for (int k = 0; k < K2 / 4; ++k) zr[k] = gz[k];

    u32 w[K2];
    float bb = 0.f;
    if (tid < G3) {
        const float2* wrow = (const float2*)(W + (size_t)tid * (2 * K2));
        #pragma unroll
        for (int j = 0; j < K2; ++j) { float2 v = wrow[j]; w[j] = packh2(v.x, v.y); }
        bb = bias[tid];
    }

    for (int m = 0; m < 64; ++m) {
        if (tid < G3) {
            float a0 = bb, a1 = 0.f;
            #pragma unroll
            for (int k = 0; k < K2 / 4; ++k) {
                u32 p0 = rdlane(zr[k].x, m);
                u32 p1 = rdlane(zr[k].y, m);
                u32 p2 = rdlane(zr[k].z, m);
                u32 p3 = rdlane(zr[k].w, m);
                a0 = fdot2(w[4 * k + 0], p0, a0);
                a1 = fdot2(w[4 * k + 1], p1, a1);
                a0 = fdot2(w[4 * k + 2], p2, a0);
                a1 = fdot2(w[4 * k + 3], p3, a1);
            }
            out[out_base + (size_t)m * G3 + tid] = a0 + a1;
        }
    }
}

// ---------------------------------------------------------------------------
// K3: GRU scan chunk. 64 blocks, 512 threads, ONE gate-row/thread (w[80] u32,
// ~105 VGPR -> no spill). h broadcast: 1 ds_read_b128 + v_readlane per wave.
// ---------------------------------------------------------------------------
__global__ __launch_bounds__(512, 2) void gru_scan_kernel(
    const float* __restrict__ xg,        // [B, TC, 480] f32 (chunk)
    const float* __restrict__ w_hh,      // [480, 160] f32
    const float* __restrict__ b_hh,      // [480]
    float* __restrict__ h_state,         // [B, 160] f32 carry
    unsigned short* __restrict__ h_out,  // [B, TC, 160] f16, or nullptr
    int first)
{
    const int b = blockIdx.x;
    const int tid = threadIdx.x;
    const int lane = tid & 63;
    __shared__ uint4 ld_h4[20];   // h as f16 pairs (80 u32)
    __shared__ float ld_g[480];
    __shared__ float ld_xn[160];

    u32 w[80];
    float bhh = 0.f;
    if (tid < G3) {
        const float2* wrow = (const float2*)(w_hh + (size_t)tid * HH);
        #pragma unroll
        for (int j = 0; j < 80; ++j) { float2 v = wrow[j]; w[j] = packh2(v.x, v.y); }
        bhh = b_hh[tid];
    }
    float h = 0.f;
    if (tid < HH) {
        h = first ? 0.f : h_state[b * HH + tid];
        ((_Float16*)ld_h4)[tid] = (_Float16)h;
    }
    const float* xgp = xg + (size_t)b * TC * G3 + tid;
    float xcur = (tid < G3) ? xgp[0] : 0.f;
    __syncthreads();

    for (int t = 0; t < TC; ++t) {
        float xnext = 0.f;
        if (tid < G3 && t + 1 < TC) xnext = xgp[(size_t)(t + 1) * G3];
        if (tid < G3) {
            const uint4 hv = ld_h4[lane < 20 ? lane : 0];
            float a0 = bhh, a1 = 0.f;
            #pragma unroll
            for (int j = 0; j < 20; ++j) {
                u32 p0 = rdlane(hv.x, j);
                u32 p1 = rdlane(hv.y, j);
                u32 p2 = rdlane(hv.z, j);
                u32 p3 = rdlane(hv.w, j);
                a0 = fdot2(w[4 * j + 0], p0, a0);
                a1 = fdot2(w[4 * j + 1], p1, a1);
                a0 = fdot2(w[4 * j + 2], p2, a0);
                a1 = fdot2(w[4 * j + 3], p3, a1);
            }
            float s = a0 + a1;
            if (tid < 320) ld_g[tid] = s + xcur;
            else { ld_g[tid] = s; ld_xn[tid - 320] = xcur; }
        }
        __syncthreads();
        if (tid < HH) {
            float r = fsigmoid(ld_g[tid]);
            float u = fsigmoid(ld_g[160 + tid]);
            float n = ftanhf(ld_xn[tid] + r * ld_g[320 + tid]);
            h = (1.f - u) * n + u * h;
            ((_Float16*)ld_h4)[tid] = (_Float16)h;
            if (h_out) h_out[((size_t)b * TC + t) * HH + tid] = f2h(h);
        }
        xcur = xnext;
        __syncthreads();
    }
    if (tid < HH) h_state[b * HH + tid] = h;
}

// ---------------------------------------------------------------------------
// K4: MLP head from h2 final state.
// ---------------------------------------------------------------------------
__global__ __launch_bounds__(256) void head_kernel(
    const float* __restrict__ h_state,
    const float* __restrict__ hw1, const float* __restrict__ hb1,
    const float* __restrict__ hw2, const float* __restrict__ hb2,
    float* __restrict__ out)
{
    const int b = blockIdx.x;
    const int tid = threadIdx.x;
    __shared__ float hf[HH];
    __shared__ float q[80];
    if (tid < HH) hf[tid] = h_state[b * HH + tid];
    __syncthreads();
    if (tid < 80) {
        float a = hb1[tid];
        const float* wr = hw1 + (size_t)tid * HH;
        #pragma unroll 8
        for (int i = 0; i < HH; ++i) a = fmaf(wr[i], hf[i], a);
        q[tid] = gelu_exact(a);
    }
    __syncthreads();
    if (tid < 2) {
        float o = hb2[tid];
        const float* wr = hw2 + tid * 80;
        #pragma unroll 8
        for (int j = 0; j < 80; ++j) o = fmaf(wr[j], q[j], o);
        out[b * 2 + tid] = o;
    }
}

// ---------------------------------------------------------------------------
extern "C" void kernel_launch(void* const* d_in, const int* in_sizes, int n_in,
                              void* d_out, int out_size, void* d_ws, size_t ws_size,
                              hipStream_t stream)
{
    const float* x     = (const float*)d_in[0];
    const float* mix_w = (const float*)d_in[1];
    const float* bn_g  = (const float*)d_in[2];
    const float* bn_b  = (const float*)d_in[3];
    const float* bn_m  = (const float*)d_in[4];
    const float* bn_v  = (const float*)d_in[5];
    const float* w_ih1 = (const float*)d_in[6];
    const float* w_hh1 = (const float*)d_in[7];
    const float* b_ih1 = (const float*)d_in[8];
    const float* b_hh1 = (const float*)d_in[9];
    const float* w_ih2 = (const float*)d_in[10];
    const float* w_hh2 = (const float*)d_in[11];
    const float* b_ih2 = (const float*)d_in[12];
    const float* b_hh2 = (const float*)d_in[13];
    const float* hw1   = (const float*)d_in[14];
    const float* hb1   = (const float*)d_in[15];
    const float* hw2   = (const float*)d_in[16];
    const float* hb2   = (const float*)d_in[17];
    float* out = (float*)d_out;

    // ws (53.6 MB, proven-safe):
    //   z   f16-pairs [B,T,32]u32   16.78 MB
    //   xg  f32 chunk [B,TC,480]    31.46 MB  (shared by layer1/layer2)
    //   h1c f16 chunk [B,TC,160]     5.24 MB
    //   h1s,h2s f32 [B,160]          2 x 40 KB
    char* p = (char*)d_ws;
    u32* z_ws = (u32*)p;                  p += (size_t)BB * TT * 32 * 4;
    float* xg_ws = (float*)p;             p += (size_t)BB * TC * G3 * 4;
    unsigned short* h1c_ws = (unsigned short*)p;  p += (size_t)BB * TC * HH * 2;
    float* h1s = (float*)p;               p += (size_t)BB * HH * 4;
    float* h2s = (float*)p;

    conv_bn_gelu_kernel<<<dim3(16, BB), 256, 0, stream>>>(
        x, mix_w, bn_g, bn_b, bn_m, bn_v, z_ws);

    for (int c = 0; c < NC; ++c) {
        const int first = (c == 0) ? 1 : 0;
        xg_gemm_kernel<32><<<dim3(TC / 64, BB), 512, 0, stream>>>(
            z_ws, TT, c * TC, w_ih1, b_ih1, xg_ws);
        gru_scan_kernel<<<BB, 512, 0, stream>>>(
            xg_ws, w_hh1, b_hh1, h1s, h1c_ws, first);
        xg_gemm_kernel<80><<<dim3(TC / 64, BB), 512, 0, stream>>>(
            (const u32*)h1c_ws, TC, 0, w_ih2, b_ih2, xg_ws);
        gru_scan_kernel<<<BB, 512, 0, stream>>>(
            xg_ws, w_hh2, b_hh2, h2s, nullptr, first);
    }

    head_kernel<<<BB, 256, 0, stream>>>(h2s, hw1, hb1, hw2, hb2, out);
}

// Round 6
// 5014.267 us; speedup vs baseline: 1.1734x; 1.1734x over previous
//
#include <hip/hip_runtime.h>
#include <cmath>

#define BB 64
#define TT 2048
#define FF 64
#define HH 160
#define G3 480
#define TC 256            // time-chunk length
#define NC (TT / TC)      // 8 chunks

typedef unsigned int u32;
typedef _Float16 half2v __attribute__((ext_vector_type(2)));

__device__ __forceinline__ unsigned short f2h(float x) {
    _Float16 h = (_Float16)x;
    return __builtin_bit_cast(unsigned short, h);
}
__device__ __forceinline__ u32 packh2(float a, float b) {
    return (u32)f2h(a) | ((u32)f2h(b) << 16);
}
__device__ __forceinline__ float fdot2(u32 w, u32 v, float acc) {
    return __builtin_amdgcn_fdot2(__builtin_bit_cast(half2v, w),
                                  __builtin_bit_cast(half2v, v), acc, false);
}
__device__ __forceinline__ u32 rdlane(u32 v, int l) {
    return (u32)__builtin_amdgcn_readlane((int)v, l);
}
__device__ __forceinline__ float fsigmoid(float x) { return 1.f / (1.f + __expf(-x)); }
__device__ __forceinline__ float ftanhf(float x) {
    float xc = fminf(fmaxf(x, -15.f), 15.f);
    float e = __expf(2.f * xc);
    return 1.f - 2.f / (e + 1.f);
}
__device__ __forceinline__ float gelu_exact(float x) {
    return 0.5f * x * (1.f + erff(x * 0.70710678118654752f));
}

// pack 8 consecutive f32 of the weight row into one uint4 of f16 pairs
#define LOADW(i) { float4 va = wrow[2*(i)], vb = wrow[2*(i)+1];              \
    w##i = (uint4){packh2(va.x, va.y), packh2(va.z, va.w),                   \
                   packh2(vb.x, vb.y), packh2(vb.z, vb.w)}; }

// ---------------------------------------------------------------------------
// K1: dilated conv (k=3, dil=2, pad=2) + BN + exact GELU -> z f16 pairs [B,T,32]u32
// (unchanged — passed R1/R3/R4)
// ---------------------------------------------------------------------------
__global__ __launch_bounds__(256) void conv_bn_gelu_kernel(
    const float* __restrict__ x, const float* __restrict__ mix_w,
    const float* __restrict__ bn_g, const float* __restrict__ bn_b,
    const float* __restrict__ bn_m, const float* __restrict__ bn_v,
    u32* __restrict__ z_out)
{
    __shared__ float ws_w[3][64][64];
    __shared__ float ws_x[132][64];
    const int b  = blockIdx.y;
    const int t0 = blockIdx.x * 128;
    const int tid = threadIdx.x;
    const int f  = tid & 63;
    const int rg = tid >> 6;

    for (int idx = tid; idx < 64 * 64 * 3; idx += 256) {
        int fo = idx / 192;
        int rem = idx - fo * 192;
        int fi = rem / 3;
        int k  = rem - fi * 3;
        ws_w[k][fi][fo] = mix_w[idx];
    }
    for (int row = rg; row < 132; row += 4) {
        int t = t0 - 2 + row;
        ws_x[row][f] = (t >= 0 && t < TT) ? x[((size_t)b * TT + t) * FF + f] : 0.f;
    }
    __syncthreads();

    const float scale = bn_g[f] * rsqrtf(bn_v[f] + 1e-5f);
    const float shift = bn_b[f] - bn_m[f] * scale;

    for (int ti = rg; ti < 128; ti += 4) {
        float acc = 0.f;
        #pragma unroll
        for (int k = 0; k < 3; ++k) {
            const float* xr = &ws_x[ti + 2 * k][0];
            #pragma unroll
            for (int fi = 0; fi < 64; ++fi)
                acc = fmaf(xr[fi], ws_w[k][fi][f], acc);
        }
        float y = fmaf(acc, scale, shift);
        float z = gelu_exact(y);
        float zp = __shfl_xor(z, 1);
        if ((f & 1) == 0)
            z_out[((size_t)b * TT + (t0 + ti)) * 32 + (f >> 1)] = packh2(z, zp);
    }
}

// ---------------------------------------------------------------------------
// K2a: xg GEMM, K=64 (layer 1). Named-variable registers only, no LDS.
// Lane l holds input row (mt*64+l); rows broadcast via v_readlane.
// NOTE: macro params must NOT be named x/y/z/w (collide with member access).
// ---------------------------------------------------------------------------
#define GDOT(i, A0, A1) {                                                    \
    u32 p0 = rdlane(z##i.x, m), p1 = rdlane(z##i.y, m);                      \
    u32 p2 = rdlane(z##i.z, m), p3 = rdlane(z##i.w, m);                      \
    A0 = fdot2(w##i.x, p0, A0); A1 = fdot2(w##i.y, p1, A1);                  \
    A0 = fdot2(w##i.z, p2, A0); A1 = fdot2(w##i.w, p3, A1); }

__global__ void __launch_bounds__(512) __attribute__((amdgpu_waves_per_eu(2, 2)))
xg_gemm_k64(const u32* __restrict__ in, int in_stride_rows, int row0,
            const float* __restrict__ W, const float* __restrict__ bias,
            float* __restrict__ out)
{
    const int tid  = threadIdx.x;
    const int lane = tid & 63;
    const int b    = blockIdx.y;
    const int mt   = blockIdx.x;
    const int row  = tid < G3 ? tid : (G3 - 1);
    const size_t in_row   = (size_t)b * in_stride_rows + row0 + mt * 64 + lane;
    const size_t out_base = ((size_t)b * TC + mt * 64) * G3;

    const uint4* gz = (const uint4*)(in + in_row * 32);
    uint4 z0 = gz[0], z1 = gz[1], z2 = gz[2], z3 = gz[3];
    uint4 z4 = gz[4], z5 = gz[5], z6 = gz[6], z7 = gz[7];

    uint4 w0, w1, w2, w3, w4, w5, w6, w7;
    const float4* wrow = (const float4*)(W + (size_t)row * 64);
    LOADW(0) LOADW(1) LOADW(2) LOADW(3) __builtin_amdgcn_sched_barrier(0);
    LOADW(4) LOADW(5) LOADW(6) LOADW(7) __builtin_amdgcn_sched_barrier(0);
    const float bb = bias[row];

    for (int m = 0; m < 64; ++m) {
        float a0 = bb, a1 = 0.f, a2 = 0.f, a3 = 0.f;
        GDOT(0, a0, a1) GDOT(1, a2, a3) GDOT(2, a0, a1) GDOT(3, a2, a3)
        GDOT(4, a0, a1) GDOT(5, a2, a3) GDOT(6, a0, a1) GDOT(7, a2, a3)
        if (tid < G3)
            out[out_base + (size_t)m * G3 + row] = (a0 + a1) + (a2 + a3);
    }
}

// ---------------------------------------------------------------------------
// K2b: xg GEMM, K=160 (layer 2). Same structure, 20+20 named uint4s.
// ---------------------------------------------------------------------------
__global__ void __launch_bounds__(512) __attribute__((amdgpu_waves_per_eu(2, 2)))
xg_gemm_k160(const u32* __restrict__ in, int in_stride_rows, int row0,
             const float* __restrict__ W, const float* __restrict__ bias,
             float* __restrict__ out)
{
    const int tid  = threadIdx.x;
    const int lane = tid & 63;
    const int b    = blockIdx.y;
    const int mt   = blockIdx.x;
    const int row  = tid < G3 ? tid : (G3 - 1);
    const size_t in_row   = (size_t)b * in_stride_rows + row0 + mt * 64 + lane;
    const size_t out_base = ((size_t)b * TC + mt * 64) * G3;

    const uint4* gz = (const uint4*)(in + in_row * 80);
    uint4 z0 = gz[0], z1 = gz[1], z2 = gz[2], z3 = gz[3], z4 = gz[4];
    uint4 z5 = gz[5], z6 = gz[6], z7 = gz[7], z8 = gz[8], z9 = gz[9];
    uint4 z10 = gz[10], z11 = gz[11], z12 = gz[12], z13 = gz[13], z14 = gz[14];
    uint4 z15 = gz[15], z16 = gz[16], z17 = gz[17], z18 = gz[18], z19 = gz[19];

    uint4 w0, w1, w2, w3, w4, w5, w6, w7, w8, w9, w10, w11, w12, w13, w14,
        w15, w16, w17, w18, w19;
    const float4* wrow = (const float4*)(W + (size_t)row * 160);
    LOADW(0)  LOADW(1)  LOADW(2)  LOADW(3)  __builtin_amdgcn_sched_barrier(0);
    LOADW(4)  LOADW(5)  LOADW(6)  LOADW(7)  __builtin_amdgcn_sched_barrier(0);
    LOADW(8)  LOADW(9)  LOADW(10) LOADW(11) __builtin_amdgcn_sched_barrier(0);
    LOADW(12) LOADW(13) LOADW(14) LOADW(15) __builtin_amdgcn_sched_barrier(0);
    LOADW(16) LOADW(17) LOADW(18) LOADW(19) __builtin_amdgcn_sched_barrier(0);
    const float bb = bias[row];

    for (int m = 0; m < 64; ++m) {
        float a0 = bb, a1 = 0.f, a2 = 0.f, a3 = 0.f;
        GDOT(0, a0, a1)  GDOT(1, a2, a3)  GDOT(2, a0, a1)  GDOT(3, a2, a3)
        GDOT(4, a0, a1)  GDOT(5, a2, a3)  GDOT(6, a0, a1)  GDOT(7, a2, a3)
        GDOT(8, a0, a1)  GDOT(9, a2, a3)  GDOT(10, a0, a1) GDOT(11, a2, a3)
        GDOT(12, a0, a1) GDOT(13, a2, a3) GDOT(14, a0, a1) GDOT(15, a2, a3)
        GDOT(16, a0, a1) GDOT(17, a2, a3) GDOT(18, a0, a1) GDOT(19, a2, a3)
        if (tid < G3)
            out[out_base + (size_t)m * G3 + row] = (a0 + a1) + (a2 + a3);
    }
}

// ---------------------------------------------------------------------------
// K3: GRU scan chunk. 64 blocks, 512 threads, one gate-row/thread.
// W_hh f16-packed in 20 NAMED uint4s (no array -> no scratch demotion).
// h broadcast: 1 ds_read_b128 + v_readlane. Branch-free main loop.
// ---------------------------------------------------------------------------
#define SDOT(i, A0, A1) {                                                    \
    u32 p0 = rdlane(hv.x, (i)), p1 = rdlane(hv.y, (i));                      \
    u32 p2 = rdlane(hv.z, (i)), p3 = rdlane(hv.w, (i));                      \
    A0 = fdot2(w##i.x, p0, A0); A1 = fdot2(w##i.y, p1, A1);                  \
    A0 = fdot2(w##i.z, p2, A0); A1 = fdot2(w##i.w, p3, A1); }

template<bool WRITE_H>
__global__ void __launch_bounds__(512) __attribute__((amdgpu_waves_per_eu(2, 2)))
gru_scan_kernel(const float* __restrict__ xg,        // [B, TC, 480] f32 chunk
                const float* __restrict__ w_hh,      // [480, 160] f32
                const float* __restrict__ b_hh,      // [480]
                float* __restrict__ h_state,         // [B, 160] f32 carry
                unsigned short* __restrict__ h_out,  // [B, TC, 160] f16
                int first)
{
    const int b = blockIdx.x;
    const int tid = threadIdx.x;
    const int lane = tid & 63;
    const int row = tid < G3 ? tid : (G3 - 1);
    __shared__ uint4 ld_h4[20];   // h as f16 pairs (80 u32)
    __shared__ float ld_g[512];
    __shared__ float ld_xn[192];

    uint4 w0, w1, w2, w3, w4, w5, w6, w7, w8, w9, w10, w11, w12, w13, w14,
        w15, w16, w17, w18, w19;
    const float4* wrow = (const float4*)(w_hh + (size_t)row * HH);
    LOADW(0)  LOADW(1)  LOADW(2)  LOADW(3)  __builtin_amdgcn_sched_barrier(0);
    LOADW(4)  LOADW(5)  LOADW(6)  LOADW(7)  __builtin_amdgcn_sched_barrier(0);
    LOADW(8)  LOADW(9)  LOADW(10) LOADW(11) __builtin_amdgcn_sched_barrier(0);
    LOADW(12) LOADW(13) LOADW(14) LOADW(15) __builtin_amdgcn_sched_barrier(0);
    LOADW(16) LOADW(17) LOADW(18) LOADW(19) __builtin_amdgcn_sched_barrier(0);
    const float bhh = b_hh[row];

    float h = 0.f;
    if (tid < HH) {
        h = first ? 0.f : h_state[b * HH + tid];
        ((_Float16*)ld_h4)[tid] = (_Float16)h;
    }
    const float* xgp = xg + (size_t)b * TC * G3 + row;
    float xcur = xgp[0];
    __syncthreads();

    for (int t = 0; t < TC; ++t) {
        const int tn = (t + 1 < TC) ? (t + 1) : t;
        const float xnext = xgp[(size_t)tn * G3];
        const uint4 hv = ld_h4[lane < 20 ? lane : 0];
        float a0 = bhh, a1 = 0.f, a2 = 0.f, a3 = 0.f;
        SDOT(0, a0, a1)  SDOT(1, a2, a3)  SDOT(2, a0, a1)  SDOT(3, a2, a3)
        SDOT(4, a0, a1)  SDOT(5, a2, a3)  SDOT(6, a0, a1)  SDOT(7, a2, a3)
        SDOT(8, a0, a1)  SDOT(9, a2, a3)  SDOT(10, a0, a1) SDOT(11, a2, a3)
        SDOT(12, a0, a1) SDOT(13, a2, a3) SDOT(14, a0, a1) SDOT(15, a2, a3)
        SDOT(16, a0, a1) SDOT(17, a2, a3) SDOT(18, a0, a1) SDOT(19, a2, a3)
        const float s = (a0 + a1) + (a2 + a3);
        if (tid < 320) ld_g[tid] = s + xcur;
        else { ld_g[tid] = s; ld_xn[tid - 320] = xcur; }
        __syncthreads();
        if (tid < HH) {
            float r = fsigmoid(ld_g[tid]);
            float u = fsigmoid(ld_g[160 + tid]);
            float n = ftanhf(ld_xn[tid] + r * ld_g[320 + tid]);
            h = (1.f - u) * n + u * h;
            ((_Float16*)ld_h4)[tid] = (_Float16)h;
            if (WRITE_H) h_out[((size_t)b * TC + t) * HH + tid] = f2h(h);
        }
        xcur = xnext;
        __syncthreads();
    }
    if (tid < HH) h_state[b * HH + tid] = h;
}

// ---------------------------------------------------------------------------
// K4: MLP head from h2 final state.
// ---------------------------------------------------------------------------
__global__ __launch_bounds__(256) void head_kernel(
    const float* __restrict__ h_state,
    const float* __restrict__ hw1, const float* __restrict__ hb1,
    const float* __restrict__ hw2, const float* __restrict__ hb2,
    float* __restrict__ out)
{
    const int b = blockIdx.x;
    const int tid = threadIdx.x;
    __shared__ float hf[HH];
    __shared__ float q[80];
    if (tid < HH) hf[tid] = h_state[b * HH + tid];
    __syncthreads();
    if (tid < 80) {
        float a = hb1[tid];
        const float* wr = hw1 + (size_t)tid * HH;
        #pragma unroll 8
        for (int i = 0; i < HH; ++i) a = fmaf(wr[i], hf[i], a);
        q[tid] = gelu_exact(a);
    }
    __syncthreads();
    if (tid < 2) {
        float o = hb2[tid];
        const float* wr = hw2 + tid * 80;
        #pragma unroll 8
        for (int j = 0; j < 80; ++j) o = fmaf(wr[j], q[j], o);
        out[b * 2 + tid] = o;
    }
}

// ---------------------------------------------------------------------------
extern "C" void kernel_launch(void* const* d_in, const int* in_sizes, int n_in,
                              void* d_out, int out_size, void* d_ws, size_t ws_size,
                              hipStream_t stream)
{
    const float* x     = (const float*)d_in[0];
    const float* mix_w = (const float*)d_in[1];
    const float* bn_g  = (const float*)d_in[2];
    const float* bn_b  = (const float*)d_in[3];
    const float* bn_m  = (const float*)d_in[4];
    const float* bn_v  = (const float*)d_in[5];
    const float* w_ih1 = (const float*)d_in[6];
    const float* w_hh1 = (const float*)d_in[7];
    const float* b_ih1 = (const float*)d_in[8];
    const float* b_hh1 = (const float*)d_in[9];
    const float* w_ih2 = (const float*)d_in[10];
    const float* w_hh2 = (const float*)d_in[11];
    const float* b_ih2 = (const float*)d_in[12];
    const float* b_hh2 = (const float*)d_in[13];
    const float* hw1   = (const float*)d_in[14];
    const float* hb1   = (const float*)d_in[15];
    const float* hw2   = (const float*)d_in[16];
    const float* hb2   = (const float*)d_in[17];
    float* out = (float*)d_out;

    // ws (53.6 MB, proven-safe):
    //   z   f16-pairs [B,T,32]u32   16.78 MB
    //   xg  f32 chunk [B,TC,480]    31.46 MB  (shared by layer1/layer2)
    //   h1c f16 chunk [B,TC,160]     5.24 MB
    //   h1s,h2s f32 [B,160]          2 x 40 KB
    char* p = (char*)d_ws;
    u32* z_ws = (u32*)p;                  p += (size_t)BB * TT * 32 * 4;
    float* xg_ws = (float*)p;             p += (size_t)BB * TC * G3 * 4;
    unsigned short* h1c_ws = (unsigned short*)p;  p += (size_t)BB * TC * HH * 2;
    float* h1s = (float*)p;               p += (size_t)BB * HH * 4;
    float* h2s = (float*)p;

    conv_bn_gelu_kernel<<<dim3(16, BB), 256, 0, stream>>>(
        x, mix_w, bn_g, bn_b, bn_m, bn_v, z_ws);

    for (int c = 0; c < NC; ++c) {
        const int first = (c == 0) ? 1 : 0;
        xg_gemm_k64<<<dim3(TC / 64, BB), 512, 0, stream>>>(
            z_ws, TT, c * TC, w_ih1, b_ih1, xg_ws);
        gru_scan_kernel<true><<<BB, 512, 0, stream>>>(
            xg_ws, w_hh1, b_hh1, h1s, h1c_ws, first);
        xg_gemm_k160<<<dim3(TC / 64, BB), 512, 0, stream>>>(
            (const u32*)h1c_ws, TC, 0, w_ih2, b_ih2, xg_ws);
        gru_scan_kernel<false><<<BB, 512, 0, stream>>>(
            xg_ws, w_hh2, b_hh2, h2s, nullptr, first);
    }

    head_kernel<<<BB, 256, 0, stream>>>(h2s, hw1, hb1, hw2, hb2, out);
}